// Round 10
// baseline (4660.291 us; speedup 1.0000x reference)
//
#include <hip/hip_runtime.h>
#include <math.h>

#define B_    16
#define NP_   64
#define J_    17
#define C_    480
#define H_    128
#define W_    128
#define L_    4
#define HW_   (H_ * W_)
#define NSAMP (B_ * NP_)      // 1024
#define MROWS (NSAMP * J_)    // 17408
#define EPS_  1e-5f
#define NMAT  (1 + 2 * L_)
#define NPAD  512
#define TC    96
#define TS    64
#define NBLK_ 544             // persistent grid; 544 % 8 == 0; 3 blocks/CU -> capacity 768

typedef __attribute__((ext_vector_type(8))) short bf16x8;
typedef __attribute__((ext_vector_type(4))) short bf16x4;
typedef __attribute__((ext_vector_type(4))) float f32x4;

__device__ __forceinline__ unsigned short f2bf(float f) {
    unsigned int u = __float_as_uint(f);
    unsigned int r = (u + 0x7fffu + ((u >> 16) & 1u)) >> 16;
    return (unsigned short)r;
}
__device__ __forceinline__ float bf2f(unsigned short h) {
    return __uint_as_float(((unsigned int)h) << 16);
}

#define GLD16(gsrc, ldst)                                                                 \
    __builtin_amdgcn_global_load_lds((const __attribute__((address_space(1))) void*)(gsrc), \
                                     (__attribute__((address_space(3))) void*)(ldst), 16, 0, 0)

// ---------------- device-scope grid barrier (8 contention-split lines, monotonic) ----------------
__device__ __forceinline__ void gridbar(unsigned* cnt, int ph, int bid) {
    __syncthreads();
    if (threadIdx.x == 0) {
        __threadfence();   // release: make this block's writes device-visible
        __hip_atomic_fetch_add(&cnt[(bid & 7) * 16], 1u, __ATOMIC_RELEASE, __HIP_MEMORY_SCOPE_AGENT);
        unsigned target = (unsigned)ph * (unsigned)NBLK_;
        for (;;) {
            unsigned s = 0;
            #pragma unroll
            for (int i = 0; i < 8; ++i)
                s += __hip_atomic_load(&cnt[i * 16], __ATOMIC_ACQUIRE, __HIP_MEMORY_SCOPE_AGENT);
            if (s >= target) break;
            __builtin_amdgcn_s_sleep(2);
        }
        __threadfence();   // acquire side
    }
    __syncthreads();
}

// ---------------- weight prep (runs as its own kernel; also resets barrier counters) ----------------
__global__ __launch_bounds__(256) void k_wsplit(const float* __restrict__ Wh,
                                                const float* __restrict__ Wres,
                                                const float* __restrict__ Wp1,
                                                short* __restrict__ WtH,
                                                short* __restrict__ WpH,
                                                unsigned* __restrict__ cnt) {
    if (blockIdx.x == 0 && threadIdx.x < 256) cnt[threadIdx.x] = 0u;   // reset barrier lines
    int gid = blockIdx.x * 256 + threadIdx.x;
    const int t1 = NMAT * NPAD * C_;
    const int t2 = NPAD * 3 * C_;
    if (gid < t1) {
        int m   = gid / (NPAD * C_);
        int rem = gid % (NPAD * C_);
        int n = rem / C_;
        int k = rem % C_;
        float v = 0.f;
        if (n < C_) {
            const float* src = (m == 0) ? Wh : (Wres + (size_t)(m - 1) * C_ * C_);
            v = src[(size_t)k * C_ + n];
        }
        WtH[gid] = (short)f2bf(v);
    } else if (gid < t1 + t2) {
        int g2 = gid - t1;
        int n = g2 / (3 * C_);
        int k = g2 % (3 * C_);
        float v = (n < C_) ? Wp1[(size_t)n * 3 * C_ + k] : 0.f;
        WpH[g2] = (short)f2bf(v);
    }
}

// ---------------- GEMM tile (R8-validated 3-buffer counted-vmcnt loop, verbatim) ----------------
template <bool ADD>
__device__ void gemm_tile(char* smem, int row0, int col0,
                          const short* __restrict__ A, const short* __restrict__ Bm,
                          const float* __restrict__ bias, const float* __restrict__ bn4,
                          const short* res, short* out, int N, int K) {
    short* lds = (short*)smem;   // 3 bufs x [sA|sB] = 48 KB
    const int tid  = threadIdx.x;
    const int lane = tid & 63;
    const int wid  = tid >> 6;
    const int wm0  = (wid >> 1) * 64;
    const int wn0  = (wid & 1) * 64;

    f32x4 acc[4][4];
    #pragma unroll
    for (int i = 0; i < 4; i++)
        #pragma unroll
        for (int j = 0; j < 4; j++) acc[i][j] = (f32x4){0.f, 0.f, 0.f, 0.f};

    const int kq = lane >> 4;
    const int fr = lane & 15;

    int r_[2], cq_[2];
    #pragma unroll
    for (int t = 0; t < 2; ++t) {
        int p = (2 * wid + t) * 1024 + lane * 16;
        int v = p >> 6;
        int r = v ^ ((v >> 2) & 1);
        r_[t]  = r;
        cq_[t] = ((p >> 4) & 3) ^ (r & 3);
    }
    const short* pA0 = A  + (size_t)(row0 + r_[0]) * K + cq_[0] * 8;
    const short* pA1 = A  + (size_t)(row0 + r_[1]) * K + cq_[1] * 8;
    const short* pB0 = Bm + (size_t)(col0 + r_[0]) * K + cq_[0] * 8;
    const short* pB1 = Bm + (size_t)(col0 + r_[1]) * K + cq_[1] * 8;
    const int a0 = (2 * wid + 0) * 1024;
    const int a1 = (2 * wid + 1) * 1024;

    const int NS = K / 32;
    {
        char* lb = (char*)lds;
        GLD16(pA0, lb + a0);             GLD16(pA1, lb + a1);
        GLD16(pB0, lb + 8192 + a0);      GLD16(pB1, lb + 8192 + a1);
        char* lb1 = (char*)lds + 16384;
        GLD16(pA0 + 32, lb1 + a0);       GLD16(pA1 + 32, lb1 + a1);
        GLD16(pB0 + 32, lb1 + 8192 + a0);GLD16(pB1 + 32, lb1 + 8192 + a1);
    }

    for (int ks = 0; ks < NS; ++ks) {
        if (ks + 2 < NS) {
            const int kk = (ks + 2) * 32;
            char* lb = (char*)lds + ((ks + 2) % 3) * 16384;
            GLD16(pA0 + kk, lb + a0);        GLD16(pA1 + kk, lb + a1);
            GLD16(pB0 + kk, lb + 8192 + a0); GLD16(pB1 + kk, lb + 8192 + a1);
            asm volatile("s_waitcnt vmcnt(8)" ::: "memory");
        } else if (ks + 1 < NS) {
            asm volatile("s_waitcnt vmcnt(4)" ::: "memory");
        } else {
            asm volatile("s_waitcnt vmcnt(0)" ::: "memory");
        }
        __builtin_amdgcn_sched_barrier(0);
        asm volatile("s_barrier" ::: "memory");

        const short* lbc = lds + (ks % 3) * 8192;
        bf16x8 fa[4], fb[4];
        #pragma unroll
        for (int mf = 0; mf < 4; ++mf) {
            int r  = wm0 + mf * 16 + fr;
            int so = ((r * 64 + kq * 16) ^ ((r & 7) << 4)) >> 1;
            fa[mf] = *reinterpret_cast<const bf16x8*>(lbc + so);
        }
        #pragma unroll
        for (int nf = 0; nf < 4; ++nf) {
            int r  = wn0 + nf * 16 + fr;
            int so = ((r * 64 + kq * 16) ^ ((r & 7) << 4)) >> 1;
            fb[nf] = *reinterpret_cast<const bf16x8*>(lbc + 4096 + so);
        }
        __builtin_amdgcn_s_setprio(1);
        #pragma unroll
        for (int mf = 0; mf < 4; ++mf)
            #pragma unroll
            for (int nf = 0; nf < 4; ++nf)
                acc[mf][nf] = __builtin_amdgcn_mfma_f32_16x16x32_bf16(fa[mf], fb[nf], acc[mf][nf], 0, 0, 0);
        __builtin_amdgcn_s_setprio(0);
        asm volatile("s_barrier" ::: "memory");
    }

    const int rq = lane >> 4;
    #pragma unroll
    for (int nf = 0; nf < 4; ++nf) {
        int col = col0 + wn0 + nf * 16 + fr;
        if (col >= N) continue;
        float bia = bias[col];
        float g   = bn4[col];
        float be  = bn4[N + col];
        float mu  = bn4[2 * N + col];
        float va  = bn4[3 * N + col];
        float sc  = rsqrtf(va + EPS_) * g;
        #pragma unroll
        for (int mf = 0; mf < 4; ++mf) {
            #pragma unroll
            for (int r = 0; r < 4; ++r) {
                int row = row0 + wm0 + mf * 16 + rq * 4 + r;
                float v = acc[mf][nf][r] + bia;
                v = (v - mu) * sc + be;
                v = fmaxf(v, 0.f);
                if (ADD) v += bf2f((unsigned short)res[(size_t)row * N + col]);
                out[(size_t)row * N + col] = (short)f2bf(v);
            }
        }
    }
}

// ---------------- the persistent mega-kernel: all phases, grid barriers between ----------------
__global__ void __launch_bounds__(256, 3)
k_mega(const float* __restrict__ features, const float* __restrict__ coords,
       const int* __restrict__ center, const float* __restrict__ adj,
       const float* __restrict__ bh, const float* __restrict__ bn_head,
       const float* __restrict__ bres, const float* __restrict__ bn_res,
       const float* __restrict__ bp1, const float* __restrict__ bn_pred,
       const float* __restrict__ Wp2, const float* __restrict__ bp2,
       const short* __restrict__ WtH, const short* __restrict__ WpH,
       short* nhwc, short* bufX, short* bufH, short* AhB,
       short* featsB, short* bufP, unsigned* cnt, float* out) {
    __shared__ __align__(16) char smem[49152];
    const int bid = blockIdx.x;
    const int tid = threadIdx.x;
    int ph = 0;

    // ---- P0: NCHW f32 -> NHWC bf16 transpose (grid-stride over 20480 tiles) ----
    {
        float (*t)[TS + 1] = (float (*)[TS + 1])smem;   // [TC][TS+1] = 24.96 KB
        const int ntile = (HW_ / TS) * (C_ / TC) * B_;
        for (int tile = bid; tile < ntile; tile += NBLK_) {
            int b   = tile / ((HW_ / TS) * (C_ / TC));
            int rem = tile % ((HW_ / TS) * (C_ / TC));
            int cb  = rem / (HW_ / TS);
            int sb  = rem % (HW_ / TS);
            int c0 = cb * TC, s0 = sb * TS;
            const float* src = features + ((size_t)b * C_ + c0) * HW_ + s0;
            int cy = tid >> 6, sx = tid & 63;
            #pragma unroll
            for (int i = 0; i < TC / 4; ++i)
                t[cy + i * 4][sx] = src[(size_t)(cy + i * 4) * HW_ + sx];
            __syncthreads();
            int sy = tid >> 2;
            int cx = (tid & 3) * (TC / 4);
            short* dst = nhwc + ((size_t)b * HW_ + s0 + sy) * C_ + c0 + cx;
            alignas(16) unsigned short tmp[TC / 4];
            #pragma unroll
            for (int i = 0; i < TC / 4; ++i) tmp[i] = f2bf(t[cx + i][sy]);
            #pragma unroll
            for (int i = 0; i < 3; ++i)
                *reinterpret_cast<uint4*>(dst + i * 8) = *reinterpret_cast<const uint4*>(tmp + i * 8);
            __syncthreads();   // guard t reuse
        }
    }
    gridbar(cnt, ++ph, bid);

    // ---- P1: bilinear gather + head mix -> bf16 A (grid-stride over samples) ----
    {
        float* sX   = (float*)smem;                    // [J][C] 32.6 KB
        float* sadj = sX + J_ * C_;                    // 289 f
        float* sw   = sadj + J_ * J_;                  // [J][4]
        int*   si   = (int*)(sw + J_ * 4);             // [J]
        for (int n = bid; n < NSAMP; n += NBLK_) {
            int b = n / NP_;
            for (int t2 = tid; t2 < J_ * J_; t2 += 256) sadj[t2] = adj[t2];
            if (tid < J_) {
                int j = tid;
                int p = n * J_ + j;
                float x = coords[p * 2 + 0];
                float y = coords[p * 2 + 1];
                float x0f = fminf(fmaxf(floorf(x), 0.f), (float)(W_ - 2));
                float y0f = fminf(fmaxf(floorf(y), 0.f), (float)(H_ - 2));
                float wx = x - x0f, wy = y - y0f;
                sw[j * 4 + 0] = (1.f - wx) * (1.f - wy);
                sw[j * 4 + 1] = wx * (1.f - wy);
                sw[j * 4 + 2] = (1.f - wx) * wy;
                sw[j * 4 + 3] = wx * wy;
                si[j] = (int)y0f * W_ + (int)x0f;
            }
            __syncthreads();
            const short* base = nhwc + (size_t)b * HW_ * C_;
            for (int idx = tid; idx < J_ * (C_ / 8); idx += 256) {
                int j  = idx / (C_ / 8);
                int c8 = (idx - j * (C_ / 8)) * 8;
                const short* p00 = base + (size_t)si[j] * C_ + c8;
                bf16x8 v00 = *reinterpret_cast<const bf16x8*>(p00);
                bf16x8 v01 = *reinterpret_cast<const bf16x8*>(p00 + C_);
                bf16x8 v10 = *reinterpret_cast<const bf16x8*>(p00 + W_ * C_);
                bf16x8 v11 = *reinterpret_cast<const bf16x8*>(p00 + W_ * C_ + C_);
                float w0 = sw[j * 4], w1 = sw[j * 4 + 1], w2 = sw[j * 4 + 2], w3 = sw[j * 4 + 3];
                #pragma unroll
                for (int e = 0; e < 8; ++e)
                    sX[j * C_ + c8 + e] = bf2f((unsigned short)v00[e]) * w0 +
                                          bf2f((unsigned short)v01[e]) * w1 +
                                          bf2f((unsigned short)v10[e]) * w2 +
                                          bf2f((unsigned short)v11[e]) * w3;
            }
            __syncthreads();
            size_t obase = (size_t)n * J_ * C_;
            for (int c = tid; c < C_; c += 256) {
                float xv[J_];
                #pragma unroll
                for (int k = 0; k < J_; k++) xv[k] = sX[k * C_ + c];
                #pragma unroll
                for (int j = 0; j < J_; j++) {
                    float s = 0.f;
                    #pragma unroll
                    for (int k = 0; k < J_; k++) s += sadj[j * J_ + k] * xv[k];
                    AhB[obase + (size_t)j * C_ + c] = (short)f2bf(s);
                }
            }
            __syncthreads();   // guard smem reuse
        }
    }
    gridbar(cnt, ++ph, bid);

    // conv tile assignment: bijective XCD-chunk swizzle over 544 tiles (4 col x 136 row)
    const int cpx = NBLK_ >> 3;
    const int swz = (bid & 7) * cpx + (bid >> 3);
    const int grow0 = (swz >> 2) * 128;
    const int gcol0 = (swz & 3) * 128;

    // ---- P2: head GEMM ----
    gemm_tile<false>(smem, grow0, gcol0, AhB, WtH, bh, bn_head, nullptr, bufH, C_, C_);
    gridbar(cnt, ++ph, bid);

    // ---- residual layers ----
    for (int i = 0; i < L_; i++) {
        int m1 = 1 + 2 * i, m2 = 2 + 2 * i;
        // mix bufH -> AhB (512 units of 2 samples)
        if (bid < 512) {
            float* sadj = (float*)smem;
            for (int t2 = tid; t2 < J_ * J_; t2 += 256) sadj[t2] = adj[t2];
            __syncthreads();
            if (tid < 240) {
                int n  = bid * 2 + (tid / 120);
                int c4 = (tid % 120) * 4;
                const short* xb = bufH + (size_t)n * J_ * C_ + c4;
                float xf[J_][4];
                #pragma unroll
                for (int k = 0; k < J_; k++) {
                    bf16x4 v = *reinterpret_cast<const bf16x4*>(xb + (size_t)k * C_);
                    #pragma unroll
                    for (int e = 0; e < 4; ++e) xf[k][e] = bf2f((unsigned short)v[e]);
                }
                short* yb = AhB + (size_t)n * J_ * C_ + c4;
                #pragma unroll
                for (int j = 0; j < J_; j++) {
                    float a0 = 0.f, a1 = 0.f, a2 = 0.f, a3 = 0.f;
                    #pragma unroll
                    for (int k = 0; k < J_; k++) {
                        float w = sadj[j * J_ + k];
                        a0 = fmaf(w, xf[k][0], a0);
                        a1 = fmaf(w, xf[k][1], a1);
                        a2 = fmaf(w, xf[k][2], a2);
                        a3 = fmaf(w, xf[k][3], a3);
                    }
                    bf16x4 o = {(short)f2bf(a0), (short)f2bf(a1), (short)f2bf(a2), (short)f2bf(a3)};
                    *reinterpret_cast<bf16x4*>(yb + (size_t)j * C_) = o;
                }
            }
        }
        gridbar(cnt, ++ph, bid);
        gemm_tile<false>(smem, grow0, gcol0, AhB, WtH + (size_t)m1 * NPAD * C_,
                         bres + (size_t)(2 * i) * C_, bn_res + (size_t)(2 * i) * 4 * C_,
                         nullptr, bufX, C_, C_);
        gridbar(cnt, ++ph, bid);
        // mix bufX -> AhB
        if (bid < 512) {
            float* sadj = (float*)smem;
            for (int t2 = tid; t2 < J_ * J_; t2 += 256) sadj[t2] = adj[t2];
            __syncthreads();
            if (tid < 240) {
                int n  = bid * 2 + (tid / 120);
                int c4 = (tid % 120) * 4;
                const short* xb = bufX + (size_t)n * J_ * C_ + c4;
                float xf[J_][4];
                #pragma unroll
                for (int k = 0; k < J_; k++) {
                    bf16x4 v = *reinterpret_cast<const bf16x4*>(xb + (size_t)k * C_);
                    #pragma unroll
                    for (int e = 0; e < 4; ++e) xf[k][e] = bf2f((unsigned short)v[e]);
                }
                short* yb = AhB + (size_t)n * J_ * C_ + c4;
                #pragma unroll
                for (int j = 0; j < J_; j++) {
                    float a0 = 0.f, a1 = 0.f, a2 = 0.f, a3 = 0.f;
                    #pragma unroll
                    for (int k = 0; k < J_; k++) {
                        float w = sadj[j * J_ + k];
                        a0 = fmaf(w, xf[k][0], a0);
                        a1 = fmaf(w, xf[k][1], a1);
                        a2 = fmaf(w, xf[k][2], a2);
                        a3 = fmaf(w, xf[k][3], a3);
                    }
                    bf16x4 o = {(short)f2bf(a0), (short)f2bf(a1), (short)f2bf(a2), (short)f2bf(a3)};
                    *reinterpret_cast<bf16x4*>(yb + (size_t)j * C_) = o;
                }
            }
        }
        gridbar(cnt, ++ph, bid);
        gemm_tile<true>(smem, grow0, gcol0, AhB, WtH + (size_t)m2 * NPAD * C_,
                        bres + (size_t)(2 * i + 1) * C_, bn_res + (size_t)(2 * i + 1) * 4 * C_,
                        bufH, bufH, C_, C_);
        gridbar(cnt, ++ph, bid);
    }

    // ---- pool + concat + center ----
    for (int n = bid; n < NSAMP; n += NBLK_) {
        int b = n / NP_;
        const short* cen = nhwc + ((size_t)b * HW_ + center[n]) * C_;
        for (int c = tid; c < C_; c += 256) {
            float s = 0.f, m = -INFINITY;
            #pragma unroll
            for (int j = 0; j < J_; j++) {
                float v = bf2f((unsigned short)bufH[((size_t)n * J_ + j) * C_ + c]);
                s += v;
                m = fmaxf(m, v);
            }
            featsB[(size_t)n * 3 * C_ + c]          = (short)f2bf(s * (1.f / (float)J_));
            featsB[(size_t)n * 3 * C_ + C_ + c]     = (short)f2bf(m);
            featsB[(size_t)n * 3 * C_ + 2 * C_ + c] = cen[c];
        }
    }
    gridbar(cnt, ++ph, bid);

    // ---- pred GEMM: 32 tiles (8 row x 4 col), blocks 0..31 ----
    if (bid < 32)
        gemm_tile<false>(smem, (bid >> 2) * 128, (bid & 3) * 128, featsB, WpH,
                         bp1, bn_pred, nullptr, bufP, C_, 3 * C_);
    gridbar(cnt, ++ph, bid);

    // ---- final projection: 34816 outputs = 544*64 exactly... grid-stride ----
    for (int g = bid * 256 + tid; g < NSAMP * 2 * J_; g += NBLK_ * 256) {
        int m = g / (2 * J_);
        int o = g % (2 * J_);
        const short* pr = bufP + (size_t)m * C_;
        const float* wr = Wp2 + (size_t)o * C_;
        float s = 0.f;
        for (int k = 0; k < C_; k += 4) {
            s = fmaf(bf2f((unsigned short)pr[k + 0]), wr[k + 0], s);
            s = fmaf(bf2f((unsigned short)pr[k + 1]), wr[k + 1], s);
            s = fmaf(bf2f((unsigned short)pr[k + 2]), wr[k + 2], s);
            s = fmaf(bf2f((unsigned short)pr[k + 3]), wr[k + 3], s);
        }
        out[g] = s + bp2[o];
    }
}

extern "C" void kernel_launch(void* const* d_in, const int* in_sizes, int n_in,
                              void* d_out, int out_size, void* d_ws, size_t ws_size,
                              hipStream_t stream) {
    const float* features = (const float*)d_in[0];
    const float* coords   = (const float*)d_in[1];
    const int*   center   = (const int*)d_in[2];
    const float* adj      = (const float*)d_in[3];
    const float* Wh       = (const float*)d_in[4];
    const float* bh       = (const float*)d_in[5];
    const float* bn_head  = (const float*)d_in[6];
    const float* Wres     = (const float*)d_in[7];
    const float* bres     = (const float*)d_in[8];
    const float* bn_res   = (const float*)d_in[9];
    const float* Wp1      = (const float*)d_in[10];
    const float* bp1      = (const float*)d_in[11];
    const float* bn_pred  = (const float*)d_in[12];
    const float* Wp2      = (const float*)d_in[13];
    const float* bp2      = (const float*)d_in[14];
    float* out = (float*)d_out;

    // ---- workspace layout (counters first, 1 KB) ----
    char* ws = (char*)d_ws;
    unsigned* cnt = (unsigned*)ws;   ws += 1024;
    short* nhwc  = (short*)ws;   ws += (size_t)B_ * HW_ * C_ * 2;
    short* bufX  = (short*)ws;   ws += (size_t)MROWS * C_ * 2;
    short* bufH  = (short*)ws;   ws += (size_t)MROWS * C_ * 2;
    short* AhB   = (short*)ws;   ws += (size_t)MROWS * C_ * 2;
    short* featsB= (short*)ws;   ws += (size_t)NSAMP * 3 * C_ * 2;
    short* bufP  = (short*)ws;   ws += (size_t)NSAMP * C_ * 2;
    short* WtH   = (short*)ws;   ws += (size_t)NMAT * NPAD * C_ * 2;
    short* WpH   = (short*)ws;   ws += (size_t)NPAD * 3 * C_ * 2;

    int wtot = NMAT * NPAD * C_ + NPAD * 3 * C_;
    k_wsplit<<<(wtot + 255) / 256, 256, 0, stream>>>(Wh, Wres, Wp1, WtH, WpH, cnt);

    k_mega<<<NBLK_, 256, 0, stream>>>(features, coords, center, adj,
                                      bh, bn_head, bres, bn_res, bp1, bn_pred, Wp2, bp2,
                                      WtH, WpH, nhwc, bufX, bufH, AhB, featsB, bufP,
                                      cnt, out);
}

// Round 11
// 1347.061 us; speedup vs baseline: 3.4596x; 3.4596x over previous
//
#include <hip/hip_runtime.h>
#include <math.h>

#define B_    16
#define NP_   64
#define J_    17
#define C_    480
#define H_    128
#define W_    128
#define L_    4
#define HW_   (H_ * W_)
#define NSAMP (B_ * NP_)      // 1024
#define MROWS (NSAMP * J_)    // 17408
#define EPS_  1e-5f
#define NMAT  (1 + 2 * L_)
#define NPAD  512
#define TC    96
#define TS    64
#define NBLK_ 544             // persistent grid; 544 % 8 == 0; 3 blocks/CU -> capacity 768

typedef __attribute__((ext_vector_type(8))) short bf16x8;
typedef __attribute__((ext_vector_type(4))) short bf16x4;
typedef __attribute__((ext_vector_type(4))) float f32x4;

__device__ __forceinline__ unsigned short f2bf(float f) {
    unsigned int u = __float_as_uint(f);
    unsigned int r = (u + 0x7fffu + ((u >> 16) & 1u)) >> 16;
    return (unsigned short)r;
}
__device__ __forceinline__ float bf2f(unsigned short h) {
    return __uint_as_float(((unsigned int)h) << 16);
}

#define GLD16(gsrc, ldst)                                                                 \
    __builtin_amdgcn_global_load_lds((const __attribute__((address_space(1))) void*)(gsrc), \
                                     (__attribute__((address_space(3))) void*)(ldst), 16, 0, 0)

// ---------------- grid barrier v2: relaxed arrivals, master-published flag ----------------
// cnt[i*16], i<8 : arrival lines (64B apart).  cnt[192] : release flag (=phase).
// Data chain: producer stores -> threadfence -> relaxed arrive; master relaxed-sums ->
// threadfence -> relaxed flag store; consumer relaxed-polls flag -> threadfence -> loads.
__device__ __forceinline__ void gridbar(unsigned* cnt, int ph, int bid) {
    __syncthreads();
    if (threadIdx.x == 0) {
        __threadfence();
        __hip_atomic_fetch_add(&cnt[(bid & 7) * 16], 1u, __ATOMIC_RELAXED, __HIP_MEMORY_SCOPE_AGENT);
        if (bid == 0) {
            const unsigned target = (unsigned)ph * (unsigned)NBLK_;
            for (;;) {
                unsigned s = 0;
                #pragma unroll
                for (int i = 0; i < 8; ++i)
                    s += __hip_atomic_load(&cnt[i * 16], __ATOMIC_RELAXED, __HIP_MEMORY_SCOPE_AGENT);
                if (s >= target) break;
                __builtin_amdgcn_s_sleep(2);
            }
            __threadfence();
            __hip_atomic_store(&cnt[192], (unsigned)ph, __ATOMIC_RELAXED, __HIP_MEMORY_SCOPE_AGENT);
        } else {
            while (__hip_atomic_load(&cnt[192], __ATOMIC_RELAXED, __HIP_MEMORY_SCOPE_AGENT) < (unsigned)ph)
                __builtin_amdgcn_s_sleep(16);
        }
        __threadfence();
    }
    __syncthreads();
}

// ---------------- weight prep (also resets barrier lines + flag) ----------------
__global__ __launch_bounds__(256) void k_wsplit(const float* __restrict__ Wh,
                                                const float* __restrict__ Wres,
                                                const float* __restrict__ Wp1,
                                                short* __restrict__ WtH,
                                                short* __restrict__ WpH,
                                                unsigned* __restrict__ cnt) {
    if (blockIdx.x == 0 && threadIdx.x < 256) cnt[threadIdx.x] = 0u;
    int gid = blockIdx.x * 256 + threadIdx.x;
    const int t1 = NMAT * NPAD * C_;
    const int t2 = NPAD * 3 * C_;
    if (gid < t1) {
        int m   = gid / (NPAD * C_);
        int rem = gid % (NPAD * C_);
        int n = rem / C_;
        int k = rem % C_;
        float v = 0.f;
        if (n < C_) {
            const float* src = (m == 0) ? Wh : (Wres + (size_t)(m - 1) * C_ * C_);
            v = src[(size_t)k * C_ + n];
        }
        WtH[gid] = (short)f2bf(v);
    } else if (gid < t1 + t2) {
        int g2 = gid - t1;
        int n = g2 / (3 * C_);
        int k = g2 % (3 * C_);
        float v = (n < C_) ? Wp1[(size_t)n * 3 * C_ + k] : 0.f;
        WpH[g2] = (short)f2bf(v);
    }
}

// ---------------- GEMM tile (R8-validated 3-buffer counted-vmcnt loop) ----------------
template <bool ADD>
__device__ void gemm_tile(char* smem, int row0, int col0,
                          const short* __restrict__ A, const short* __restrict__ Bm,
                          const float* __restrict__ bias, const float* __restrict__ bn4,
                          const short* res, short* out, int N, int K) {
    short* lds = (short*)smem;   // 3 bufs x [sA|sB] = 48 KB
    const int tid  = threadIdx.x;
    const int lane = tid & 63;
    const int wid  = tid >> 6;
    const int wm0  = (wid >> 1) * 64;
    const int wn0  = (wid & 1) * 64;

    f32x4 acc[4][4];
    #pragma unroll
    for (int i = 0; i < 4; i++)
        #pragma unroll
        for (int j = 0; j < 4; j++) acc[i][j] = (f32x4){0.f, 0.f, 0.f, 0.f};

    const int kq = lane >> 4;
    const int fr = lane & 15;

    int r_[2], cq_[2];
    #pragma unroll
    for (int t = 0; t < 2; ++t) {
        int p = (2 * wid + t) * 1024 + lane * 16;
        int v = p >> 6;
        int r = v ^ ((v >> 2) & 1);
        r_[t]  = r;
        cq_[t] = ((p >> 4) & 3) ^ (r & 3);
    }
    const short* pA0 = A  + (size_t)(row0 + r_[0]) * K + cq_[0] * 8;
    const short* pA1 = A  + (size_t)(row0 + r_[1]) * K + cq_[1] * 8;
    const short* pB0 = Bm + (size_t)(col0 + r_[0]) * K + cq_[0] * 8;
    const short* pB1 = Bm + (size_t)(col0 + r_[1]) * K + cq_[1] * 8;
    const int a0 = (2 * wid + 0) * 1024;
    const int a1 = (2 * wid + 1) * 1024;

    const int NS = K / 32;
    {
        char* lb = (char*)lds;
        GLD16(pA0, lb + a0);             GLD16(pA1, lb + a1);
        GLD16(pB0, lb + 8192 + a0);      GLD16(pB1, lb + 8192 + a1);
        char* lb1 = (char*)lds + 16384;
        GLD16(pA0 + 32, lb1 + a0);       GLD16(pA1 + 32, lb1 + a1);
        GLD16(pB0 + 32, lb1 + 8192 + a0);GLD16(pB1 + 32, lb1 + 8192 + a1);
    }

    for (int ks = 0; ks < NS; ++ks) {
        if (ks + 2 < NS) {
            const int kk = (ks + 2) * 32;
            char* lb = (char*)lds + ((ks + 2) % 3) * 16384;
            GLD16(pA0 + kk, lb + a0);        GLD16(pA1 + kk, lb + a1);
            GLD16(pB0 + kk, lb + 8192 + a0); GLD16(pB1 + kk, lb + 8192 + a1);
            asm volatile("s_waitcnt vmcnt(8)" ::: "memory");
        } else if (ks + 1 < NS) {
            asm volatile("s_waitcnt vmcnt(4)" ::: "memory");
        } else {
            asm volatile("s_waitcnt vmcnt(0)" ::: "memory");
        }
        __builtin_amdgcn_sched_barrier(0);
        asm volatile("s_barrier" ::: "memory");

        const short* lbc = lds + (ks % 3) * 8192;
        bf16x8 fa[4], fb[4];
        #pragma unroll
        for (int mf = 0; mf < 4; ++mf) {
            int r  = wm0 + mf * 16 + fr;
            int so = ((r * 64 + kq * 16) ^ ((r & 7) << 4)) >> 1;
            fa[mf] = *reinterpret_cast<const bf16x8*>(lbc + so);
        }
        #pragma unroll
        for (int nf = 0; nf < 4; ++nf) {
            int r  = wn0 + nf * 16 + fr;
            int so = ((r * 64 + kq * 16) ^ ((r & 7) << 4)) >> 1;
            fb[nf] = *reinterpret_cast<const bf16x8*>(lbc + 4096 + so);
        }
        __builtin_amdgcn_s_setprio(1);
        #pragma unroll
        for (int mf = 0; mf < 4; ++mf)
            #pragma unroll
            for (int nf = 0; nf < 4; ++nf)
                acc[mf][nf] = __builtin_amdgcn_mfma_f32_16x16x32_bf16(fa[mf], fb[nf], acc[mf][nf], 0, 0, 0);
        __builtin_amdgcn_s_setprio(0);
        asm volatile("s_barrier" ::: "memory");
    }

    const int rq = lane >> 4;
    #pragma unroll
    for (int nf = 0; nf < 4; ++nf) {
        int col = col0 + wn0 + nf * 16 + fr;
        if (col >= N) continue;
        float bia = bias[col];
        float g   = bn4[col];
        float be  = bn4[N + col];
        float mu  = bn4[2 * N + col];
        float va  = bn4[3 * N + col];
        float sc  = rsqrtf(va + EPS_) * g;
        #pragma unroll
        for (int mf = 0; mf < 4; ++mf) {
            #pragma unroll
            for (int r = 0; r < 4; ++r) {
                int row = row0 + wm0 + mf * 16 + rq * 4 + r;
                float v = acc[mf][nf][r] + bia;
                v = (v - mu) * sc + be;
                v = fmaxf(v, 0.f);
                if (ADD) v += bf2f((unsigned short)res[(size_t)row * N + col]);
                out[(size_t)row * N + col] = (short)f2bf(v);
            }
        }
    }
}

// ---------------- the persistent mega-kernel ----------------
__global__ void __launch_bounds__(256, 3)
k_mega(const float* __restrict__ features, const float* __restrict__ coords,
       const int* __restrict__ center, const float* __restrict__ adj,
       const float* __restrict__ bh, const float* __restrict__ bn_head,
       const float* __restrict__ bres, const float* __restrict__ bn_res,
       const float* __restrict__ bp1, const float* __restrict__ bn_pred,
       const float* __restrict__ Wp2, const float* __restrict__ bp2,
       const short* __restrict__ WtH, const short* __restrict__ WpH,
       short* nhwc, short* bufX, short* bufH, short* AhB,
       short* featsB, short* bufP, unsigned* cnt, float* out) {
    __shared__ __align__(16) char smem[49152];
    const int bid = blockIdx.x;
    const int tid = threadIdx.x;
    int ph = 0;

    // ---- P0: NCHW f32 -> NHWC bf16 transpose ----
    {
        float (*t)[TS + 1] = (float (*)[TS + 1])smem;
        const int ntile = (HW_ / TS) * (C_ / TC) * B_;
        for (int tile = bid; tile < ntile; tile += NBLK_) {
            int b   = tile / ((HW_ / TS) * (C_ / TC));
            int rem = tile % ((HW_ / TS) * (C_ / TC));
            int cb  = rem / (HW_ / TS);
            int sb  = rem % (HW_ / TS);
            int c0 = cb * TC, s0 = sb * TS;
            const float* src = features + ((size_t)b * C_ + c0) * HW_ + s0;
            int cy = tid >> 6, sx = tid & 63;
            #pragma unroll
            for (int i = 0; i < TC / 4; ++i)
                t[cy + i * 4][sx] = src[(size_t)(cy + i * 4) * HW_ + sx];
            __syncthreads();
            int sy = tid >> 2;
            int cx = (tid & 3) * (TC / 4);
            short* dst = nhwc + ((size_t)b * HW_ + s0 + sy) * C_ + c0 + cx;
            alignas(16) unsigned short tmp[TC / 4];
            #pragma unroll
            for (int i = 0; i < TC / 4; ++i) tmp[i] = f2bf(t[cx + i][sy]);
            #pragma unroll
            for (int i = 0; i < 3; ++i)
                *reinterpret_cast<uint4*>(dst + i * 8) = *reinterpret_cast<const uint4*>(tmp + i * 8);
            __syncthreads();
        }
    }
    gridbar(cnt, ++ph, bid);

    // ---- P1: bilinear gather + head mix -> bf16 A ----
    {
        float* sX   = (float*)smem;
        float* sadj = sX + J_ * C_;
        float* sw   = sadj + J_ * J_;
        int*   si   = (int*)(sw + J_ * 4);
        for (int n = bid; n < NSAMP; n += NBLK_) {
            int b = n / NP_;
            for (int t2 = tid; t2 < J_ * J_; t2 += 256) sadj[t2] = adj[t2];
            if (tid < J_) {
                int j = tid;
                int p = n * J_ + j;
                float x = coords[p * 2 + 0];
                float y = coords[p * 2 + 1];
                float x0f = fminf(fmaxf(floorf(x), 0.f), (float)(W_ - 2));
                float y0f = fminf(fmaxf(floorf(y), 0.f), (float)(H_ - 2));
                float wx = x - x0f, wy = y - y0f;
                sw[j * 4 + 0] = (1.f - wx) * (1.f - wy);
                sw[j * 4 + 1] = wx * (1.f - wy);
                sw[j * 4 + 2] = (1.f - wx) * wy;
                sw[j * 4 + 3] = wx * wy;
                si[j] = (int)y0f * W_ + (int)x0f;
            }
            __syncthreads();
            const short* base = nhwc + (size_t)b * HW_ * C_;
            for (int idx = tid; idx < J_ * (C_ / 8); idx += 256) {
                int j  = idx / (C_ / 8);
                int c8 = (idx - j * (C_ / 8)) * 8;
                const short* p00 = base + (size_t)si[j] * C_ + c8;
                bf16x8 v00 = *reinterpret_cast<const bf16x8*>(p00);
                bf16x8 v01 = *reinterpret_cast<const bf16x8*>(p00 + C_);
                bf16x8 v10 = *reinterpret_cast<const bf16x8*>(p00 + W_ * C_);
                bf16x8 v11 = *reinterpret_cast<const bf16x8*>(p00 + W_ * C_ + C_);
                float w0 = sw[j * 4], w1 = sw[j * 4 + 1], w2 = sw[j * 4 + 2], w3 = sw[j * 4 + 3];
                #pragma unroll
                for (int e = 0; e < 8; ++e)
                    sX[j * C_ + c8 + e] = bf2f((unsigned short)v00[e]) * w0 +
                                          bf2f((unsigned short)v01[e]) * w1 +
                                          bf2f((unsigned short)v10[e]) * w2 +
                                          bf2f((unsigned short)v11[e]) * w3;
            }
            __syncthreads();
            size_t obase = (size_t)n * J_ * C_;
            for (int c = tid; c < C_; c += 256) {
                float xv[J_];
                #pragma unroll
                for (int k = 0; k < J_; k++) xv[k] = sX[k * C_ + c];
                #pragma unroll
                for (int j = 0; j < J_; j++) {
                    float s = 0.f;
                    #pragma unroll
                    for (int k = 0; k < J_; k++) s += sadj[j * J_ + k] * xv[k];
                    AhB[obase + (size_t)j * C_ + c] = (short)f2bf(s);
                }
            }
            __syncthreads();
        }
    }
    gridbar(cnt, ++ph, bid);

    const int cpx = NBLK_ >> 3;
    const int swz = (bid & 7) * cpx + (bid >> 3);
    const int grow0 = (swz >> 2) * 128;
    const int gcol0 = (swz & 3) * 128;

    // ---- P2: head GEMM ----
    gemm_tile<false>(smem, grow0, gcol0, AhB, WtH, bh, bn_head, nullptr, bufH, C_, C_);
    gridbar(cnt, ++ph, bid);

    // ---- residual layers ----
    for (int i = 0; i < L_; i++) {
        int m1 = 1 + 2 * i, m2 = 2 + 2 * i;
        if (bid < 512) {
            float* sadj = (float*)smem;
            for (int t2 = tid; t2 < J_ * J_; t2 += 256) sadj[t2] = adj[t2];
            __syncthreads();
            if (tid < 240) {
                int n  = bid * 2 + (tid / 120);
                int c4 = (tid % 120) * 4;
                const short* xb = bufH + (size_t)n * J_ * C_ + c4;
                float xf[J_][4];
                #pragma unroll
                for (int k = 0; k < J_; k++) {
                    bf16x4 v = *reinterpret_cast<const bf16x4*>(xb + (size_t)k * C_);
                    #pragma unroll
                    for (int e = 0; e < 4; ++e) xf[k][e] = bf2f((unsigned short)v[e]);
                }
                short* yb = AhB + (size_t)n * J_ * C_ + c4;
                #pragma unroll
                for (int j = 0; j < J_; j++) {
                    float a0 = 0.f, a1 = 0.f, a2 = 0.f, a3 = 0.f;
                    #pragma unroll
                    for (int k = 0; k < J_; k++) {
                        float w = sadj[j * J_ + k];
                        a0 = fmaf(w, xf[k][0], a0);
                        a1 = fmaf(w, xf[k][1], a1);
                        a2 = fmaf(w, xf[k][2], a2);
                        a3 = fmaf(w, xf[k][3], a3);
                    }
                    bf16x4 o = {(short)f2bf(a0), (short)f2bf(a1), (short)f2bf(a2), (short)f2bf(a3)};
                    *reinterpret_cast<bf16x4*>(yb + (size_t)j * C_) = o;
                }
            }
        }
        gridbar(cnt, ++ph, bid);
        gemm_tile<false>(smem, grow0, gcol0, AhB, WtH + (size_t)m1 * NPAD * C_,
                         bres + (size_t)(2 * i) * C_, bn_res + (size_t)(2 * i) * 4 * C_,
                         nullptr, bufX, C_, C_);
        gridbar(cnt, ++ph, bid);
        if (bid < 512) {
            float* sadj = (float*)smem;
            for (int t2 = tid; t2 < J_ * J_; t2 += 256) sadj[t2] = adj[t2];
            __syncthreads();
            if (tid < 240) {
                int n  = bid * 2 + (tid / 120);
                int c4 = (tid % 120) * 4;
                const short* xb = bufX + (size_t)n * J_ * C_ + c4;
                float xf[J_][4];
                #pragma unroll
                for (int k = 0; k < J_; k++) {
                    bf16x4 v = *reinterpret_cast<const bf16x4*>(xb + (size_t)k * C_);
                    #pragma unroll
                    for (int e = 0; e < 4; ++e) xf[k][e] = bf2f((unsigned short)v[e]);
                }
                short* yb = AhB + (size_t)n * J_ * C_ + c4;
                #pragma unroll
                for (int j = 0; j < J_; j++) {
                    float a0 = 0.f, a1 = 0.f, a2 = 0.f, a3 = 0.f;
                    #pragma unroll
                    for (int k = 0; k < J_; k++) {
                        float w = sadj[j * J_ + k];
                        a0 = fmaf(w, xf[k][0], a0);
                        a1 = fmaf(w, xf[k][1], a1);
                        a2 = fmaf(w, xf[k][2], a2);
                        a3 = fmaf(w, xf[k][3], a3);
                    }
                    bf16x4 o = {(short)f2bf(a0), (short)f2bf(a1), (short)f2bf(a2), (short)f2bf(a3)};
                    *reinterpret_cast<bf16x4*>(yb + (size_t)j * C_) = o;
                }
            }
        }
        gridbar(cnt, ++ph, bid);
        gemm_tile<true>(smem, grow0, gcol0, AhB, WtH + (size_t)m2 * NPAD * C_,
                        bres + (size_t)(2 * i + 1) * C_, bn_res + (size_t)(2 * i + 1) * 4 * C_,
                        bufH, bufH, C_, C_);
        gridbar(cnt, ++ph, bid);
    }

    // ---- pool + concat + center ----
    for (int n = bid; n < NSAMP; n += NBLK_) {
        int b = n / NP_;
        const short* cen = nhwc + ((size_t)b * HW_ + center[n]) * C_;
        for (int c = tid; c < C_; c += 256) {
            float s = 0.f, m = -INFINITY;
            #pragma unroll
            for (int j = 0; j < J_; j++) {
                float v = bf2f((unsigned short)bufH[((size_t)n * J_ + j) * C_ + c]);
                s += v;
                m = fmaxf(m, v);
            }
            featsB[(size_t)n * 3 * C_ + c]          = (short)f2bf(s * (1.f / (float)J_));
            featsB[(size_t)n * 3 * C_ + C_ + c]     = (short)f2bf(m);
            featsB[(size_t)n * 3 * C_ + 2 * C_ + c] = cen[c];
        }
    }
    gridbar(cnt, ++ph, bid);

    // ---- pred GEMM: 32 tiles (8 row x 4 col), blocks 0..31 ----
    if (bid < 32)
        gemm_tile<false>(smem, (bid >> 2) * 128, (bid & 3) * 128, featsB, WpH,
                         bp1, bn_pred, nullptr, bufP, C_, 3 * C_);
    gridbar(cnt, ++ph, bid);

    // ---- final projection ----
    for (int g = bid * 256 + tid; g < NSAMP * 2 * J_; g += NBLK_ * 256) {
        int m = g / (2 * J_);
        int o = g % (2 * J_);
        const short* pr = bufP + (size_t)m * C_;
        const float* wr = Wp2 + (size_t)o * C_;
        float s = 0.f;
        for (int k = 0; k < C_; k += 4) {
            s = fmaf(bf2f((unsigned short)pr[k + 0]), wr[k + 0], s);
            s = fmaf(bf2f((unsigned short)pr[k + 1]), wr[k + 1], s);
            s = fmaf(bf2f((unsigned short)pr[k + 2]), wr[k + 2], s);
            s = fmaf(bf2f((unsigned short)pr[k + 3]), wr[k + 3], s);
        }
        out[g] = s + bp2[o];
    }
}

extern "C" void kernel_launch(void* const* d_in, const int* in_sizes, int n_in,
                              void* d_out, int out_size, void* d_ws, size_t ws_size,
                              hipStream_t stream) {
    const float* features = (const float*)d_in[0];
    const float* coords   = (const float*)d_in[1];
    const int*   center   = (const int*)d_in[2];
    const float* adj      = (const float*)d_in[3];
    const float* Wh       = (const float*)d_in[4];
    const float* bh       = (const float*)d_in[5];
    const float* bn_head  = (const float*)d_in[6];
    const float* Wres     = (const float*)d_in[7];
    const float* bres     = (const float*)d_in[8];
    const float* bn_res   = (const float*)d_in[9];
    const float* Wp1      = (const float*)d_in[10];
    const float* bp1      = (const float*)d_in[11];
    const float* bn_pred  = (const float*)d_in[12];
    const float* Wp2      = (const float*)d_in[13];
    const float* bp2      = (const float*)d_in[14];
    float* out = (float*)d_out;

    char* ws = (char*)d_ws;
    unsigned* cnt = (unsigned*)ws;   ws += 1024;
    short* nhwc  = (short*)ws;   ws += (size_t)B_ * HW_ * C_ * 2;
    short* bufX  = (short*)ws;   ws += (size_t)MROWS * C_ * 2;
    short* bufH  = (short*)ws;   ws += (size_t)MROWS * C_ * 2;
    short* AhB   = (short*)ws;   ws += (size_t)MROWS * C_ * 2;
    short* featsB= (short*)ws;   ws += (size_t)NSAMP * 3 * C_ * 2;
    short* bufP  = (short*)ws;   ws += (size_t)NSAMP * C_ * 2;
    short* WtH   = (short*)ws;   ws += (size_t)NMAT * NPAD * C_ * 2;
    short* WpH   = (short*)ws;   ws += (size_t)NPAD * 3 * C_ * 2;

    int wtot = NMAT * NPAD * C_ + NPAD * 3 * C_;
    k_wsplit<<<(wtot + 255) / 256, 256, 0, stream>>>(Wh, Wres, Wp1, WtH, WpH, cnt);

    k_mega<<<NBLK_, 256, 0, stream>>>(features, coords, center, adj,
                                      bh, bn_head, bres, bn_res, bp1, bn_pred, Wp2, bp2,
                                      WtH, WpH, nhwc, bufX, bufH, AhB, featsB, bufP,
                                      cnt, out);
}

// Round 12
// 593.804 us; speedup vs baseline: 7.8482x; 2.2685x over previous
//
#include <hip/hip_runtime.h>
#include <math.h>

#define B_    16
#define NP_   64
#define J_    17
#define C_    480
#define H_    128
#define W_    128
#define L_    4
#define HW_   (H_ * W_)
#define NSAMP (B_ * NP_)      // 1024
#define MROWS (NSAMP * J_)    // 17408
#define EPS_  1e-5f
#define NMAT  (1 + 2 * L_)    // 9 graph-conv weight matrices
#define NPAD  512             // weight N padded to 512 rows for maskless staging
#define TC    96              // transpose tile: channels
#define TS    64              // transpose tile: spatial
#define NT_   (256 * 5 * B_)  // 20480 transpose tiles
#define NW_   11520           // wsplit blocks: (NMAT*NPAD*C_ + NPAD*3*C_)/256

typedef __attribute__((ext_vector_type(8))) short bf16x8;
typedef __attribute__((ext_vector_type(4))) short bf16x4;
typedef __attribute__((ext_vector_type(4))) float f32x4;

__device__ __forceinline__ unsigned short f2bf(float f) {
    unsigned int u = __float_as_uint(f);
    unsigned int r = (u + 0x7fffu + ((u >> 16) & 1u)) >> 16;
    return (unsigned short)r;
}
__device__ __forceinline__ float bf2f(unsigned short h) {
    return __uint_as_float(((unsigned int)h) << 16);
}

// async global->LDS, 16B per lane; LDS dest = base + lane*16 (wave-uniform base)
#define GLD16(gsrc, ldst)                                                                 \
    __builtin_amdgcn_global_load_lds((const __attribute__((address_space(1))) void*)(gsrc), \
                                     (__attribute__((address_space(3))) void*)(ldst), 16, 0, 0)

// ---------------- merged prep: NCHW->NHWC bf16 transpose (v2, float4 reads) + weight split ----------------
__global__ __launch_bounds__(256) void k_prep(const float* __restrict__ feat,
                                              const float* __restrict__ Wh,
                                              const float* __restrict__ Wres,
                                              const float* __restrict__ Wp1,
                                              short* __restrict__ nhwc,
                                              short* __restrict__ WtH,
                                              short* __restrict__ WpH) {
    int bid = blockIdx.x;
    int tid = threadIdx.x;
    if (bid < NT_) {
        // ---- transpose tile: [TC=96 c][TS=64 s], float4 reads, pad-73 LDS ----
        __shared__ float t[TC][73];   // stride 73 (mod 32 = 9): conflict-free write & read
        int sb = bid & 255;                 // 256 s-tiles
        int cb = (bid >> 8) % 5;            // 5 c-tiles
        int b  = bid / 1280;
        int c0 = cb * TC, s0 = sb * TS;
        const float* src = feat + ((size_t)b * C_ + c0) * HW_ + s0;
        #pragma unroll
        for (int i = 0; i < 6; ++i) {       // 96 rows x 16 float4 = 1536 chunks
            int f  = tid + i * 256;
            int c  = f >> 4;
            int sq = (f & 15) * 4;
            float4 v = *reinterpret_cast<const float4*>(src + (size_t)c * HW_ + sq);
            t[c][sq + 0] = v.x;
            t[c][sq + 1] = v.y;
            t[c][sq + 2] = v.z;
            t[c][sq + 3] = v.w;
        }
        __syncthreads();
        int sy = tid >> 2;                  // 0..63
        int cx = (tid & 3) * (TC / 4);      // 0,24,48,72
        short* dst = nhwc + ((size_t)b * HW_ + s0 + sy) * C_ + c0 + cx;
        alignas(16) unsigned short tmp[TC / 4];
        #pragma unroll
        for (int i = 0; i < TC / 4; ++i) tmp[i] = f2bf(t[cx + i][sy]);
        #pragma unroll
        for (int i = 0; i < 3; ++i)
            *reinterpret_cast<uint4*>(dst + i * 8) = *reinterpret_cast<const uint4*>(tmp + i * 8);
    } else {
        // ---- weight split into padded [NPAD][K] bf16 ----
        int gid = (bid - NT_) * 256 + tid;
        const int t1 = NMAT * NPAD * C_;
        const int t2 = NPAD * 3 * C_;
        if (gid < t1) {
            int m   = gid / (NPAD * C_);
            int rem = gid % (NPAD * C_);
            int n = rem / C_;
            int k = rem % C_;
            float v = 0.f;
            if (n < C_) {
                const float* src = (m == 0) ? Wh : (Wres + (size_t)(m - 1) * C_ * C_);
                v = src[(size_t)k * C_ + n];
            }
            WtH[gid] = (short)f2bf(v);
        } else if (gid < t1 + t2) {
            int g2 = gid - t1;
            int n = g2 / (3 * C_);
            int k = g2 % (3 * C_);
            float v = (n < C_) ? Wp1[(size_t)n * 3 * C_ + k] : 0.f;
            WpH[g2] = (short)f2bf(v);
        }
    }
}

// ---------------- fused bilinear gather (NHWC bf16) + head adjacency mix -> bf16 A ----------------
__global__ __launch_bounds__(256) void k_gather_mix(const short* __restrict__ nhwc,
                                                    const float* __restrict__ coords,
                                                    const float* __restrict__ adj,
                                                    short* __restrict__ Ah) {
    __shared__ float sX[J_][C_];
    __shared__ float sadj[J_ * J_];
    __shared__ float sw[J_][4];
    __shared__ int   si[J_];
    int n = blockIdx.x;                // 0..NSAMP-1
    int b = n / NP_;
    for (int t = threadIdx.x; t < J_ * J_; t += 256) sadj[t] = adj[t];
    if (threadIdx.x < J_) {
        int j = threadIdx.x;
        int p = n * J_ + j;
        float x = coords[p * 2 + 0];
        float y = coords[p * 2 + 1];
        float x0f = fminf(fmaxf(floorf(x), 0.f), (float)(W_ - 2));
        float y0f = fminf(fmaxf(floorf(y), 0.f), (float)(H_ - 2));
        float wx = x - x0f, wy = y - y0f;
        sw[j][0] = (1.f - wx) * (1.f - wy);
        sw[j][1] = wx * (1.f - wy);
        sw[j][2] = (1.f - wx) * wy;
        sw[j][3] = wx * wy;
        si[j] = (int)y0f * W_ + (int)x0f;
    }
    __syncthreads();
    const short* base = nhwc + (size_t)b * HW_ * C_;
    for (int idx = threadIdx.x; idx < J_ * (C_ / 8); idx += 256) {
        int j  = idx / (C_ / 8);
        int c8 = (idx - j * (C_ / 8)) * 8;
        const short* p00 = base + (size_t)si[j] * C_ + c8;
        bf16x8 v00 = *reinterpret_cast<const bf16x8*>(p00);
        bf16x8 v01 = *reinterpret_cast<const bf16x8*>(p00 + C_);
        bf16x8 v10 = *reinterpret_cast<const bf16x8*>(p00 + W_ * C_);
        bf16x8 v11 = *reinterpret_cast<const bf16x8*>(p00 + W_ * C_ + C_);
        float w0 = sw[j][0], w1 = sw[j][1], w2 = sw[j][2], w3 = sw[j][3];
        #pragma unroll
        for (int e = 0; e < 8; ++e) {
            sX[j][c8 + e] = bf2f((unsigned short)v00[e]) * w0 +
                            bf2f((unsigned short)v01[e]) * w1 +
                            bf2f((unsigned short)v10[e]) * w2 +
                            bf2f((unsigned short)v11[e]) * w3;
        }
    }
    __syncthreads();
    size_t obase = (size_t)n * J_ * C_;
    for (int c = threadIdx.x; c < C_; c += 256) {
        float xv[J_];
        #pragma unroll
        for (int k = 0; k < J_; k++) xv[k] = sX[k][c];
        #pragma unroll
        for (int j = 0; j < J_; j++) {
            float s = 0.f;
            #pragma unroll
            for (int k = 0; k < J_; k++) s += sadj[j * J_ + k] * xv[k];
            Ah[obase + (size_t)j * C_ + c] = (short)f2bf(s);
        }
    }
}

// ---------------- adjacency mix on bf16: A[n,j,:] = sum_k adj[j,k] X[n,k,:] ----------------
__global__ __launch_bounds__(256) void k_mix_bf16(const short* __restrict__ Xin,
                                                  const float* __restrict__ adj,
                                                  short* __restrict__ Ah) {
    __shared__ float sadj[J_ * J_];
    for (int t = threadIdx.x; t < J_ * J_; t += 256) sadj[t] = adj[t];
    __syncthreads();
    int t = threadIdx.x;
    if (t >= 240) return;
    int n  = blockIdx.x * 2 + (t / 120);
    int c4 = (t % 120) * 4;
    const short* xb = Xin + (size_t)n * J_ * C_ + c4;
    float xf[J_][4];
    #pragma unroll
    for (int k = 0; k < J_; k++) {
        bf16x4 v = *reinterpret_cast<const bf16x4*>(xb + (size_t)k * C_);
        #pragma unroll
        for (int e = 0; e < 4; ++e) xf[k][e] = bf2f((unsigned short)v[e]);
    }
    short* yb = Ah + (size_t)n * J_ * C_ + c4;
    #pragma unroll
    for (int j = 0; j < J_; j++) {
        float a0 = 0.f, a1 = 0.f, a2 = 0.f, a3 = 0.f;
        #pragma unroll
        for (int k = 0; k < J_; k++) {
            float w = sadj[j * J_ + k];
            a0 = fmaf(w, xf[k][0], a0);
            a1 = fmaf(w, xf[k][1], a1);
            a2 = fmaf(w, xf[k][2], a2);
            a3 = fmaf(w, xf[k][3], a3);
        }
        bf16x4 o = {(short)f2bf(a0), (short)f2bf(a1), (short)f2bf(a2), (short)f2bf(a3)};
        *reinterpret_cast<bf16x4*>(yb + (size_t)j * C_) = o;
    }
}

// ---------------- 1-term bf16 MFMA GEMM (R8-validated): gload_lds + 2-phase + XCD swizzle ----------------
template <bool ADD>
__global__ __launch_bounds__(256) void k_gemm_mfma(const short* __restrict__ A,
                                                   const short* __restrict__ Bm,
                                                   const float* __restrict__ bias,
                                                   const float* __restrict__ bn4,
                                                   const short* res,   // may alias out
                                                   short* out,
                                                   int M, int N, int K) {
    __shared__ short lds[2 * 2 * 4096];   // [buf][sA|sB], 32 KB

    int nwg = gridDim.x * gridDim.y;
    int lin = blockIdx.y * gridDim.x + blockIdx.x;
    int cpx = nwg >> 3;
    int swz = (lin & 7) * cpx + (lin >> 3);
    const int row0 = (swz / gridDim.x) * 128;
    const int col0 = (swz % gridDim.x) * 128;

    const int tid  = threadIdx.x;
    const int lane = tid & 63;
    const int wid  = tid >> 6;
    const int wm0  = (wid >> 1) * 64;
    const int wn0  = (wid & 1) * 64;

    f32x4 acc[4][4];
    #pragma unroll
    for (int i = 0; i < 4; i++)
        #pragma unroll
        for (int j = 0; j < 4; j++) acc[i][j] = (f32x4){0.f, 0.f, 0.f, 0.f};

    const int kq = lane >> 4;
    const int fr = lane & 15;

    int r_[2], cq_[2];
    #pragma unroll
    for (int t = 0; t < 2; ++t) {
        int p = (2 * wid + t) * 1024 + lane * 16;
        int v = p >> 6;
        int r = v ^ ((v >> 2) & 1);
        r_[t]  = r;
        cq_[t] = ((p >> 4) & 3) ^ (r & 3);
    }
    const short* pA0 = A  + (size_t)(row0 + r_[0]) * K + cq_[0] * 8;
    const short* pA1 = A  + (size_t)(row0 + r_[1]) * K + cq_[1] * 8;
    const short* pB0 = Bm + (size_t)(col0 + r_[0]) * K + cq_[0] * 8;
    const short* pB1 = Bm + (size_t)(col0 + r_[1]) * K + cq_[1] * 8;
    const int a0 = (2 * wid + 0) * 1024;
    const int a1 = (2 * wid + 1) * 1024;

    const int NS = K / 32;
    {   // prologue: stage tile 0 into buf 0
        char* lb = (char*)lds;
        GLD16(pA0, lb + a0);        GLD16(pA1, lb + a1);
        GLD16(pB0, lb + 8192 + a0); GLD16(pB1, lb + 8192 + a1);
    }
    __syncthreads();

    for (int ks = 0; ks < NS; ++ks) {
        if (ks + 1 < NS) {            // prefetch next tile into other buffer
            const int kk = (ks + 1) * 32;
            char* lb = (char*)lds + ((ks + 1) & 1) * 16384;
            GLD16(pA0 + kk, lb + a0);        GLD16(pA1 + kk, lb + a1);
            GLD16(pB0 + kk, lb + 8192 + a0); GLD16(pB1 + kk, lb + 8192 + a1);
        }
        const short* lbc = lds + (ks & 1) * 8192;
        bf16x8 fa[4], fb[4];
        #pragma unroll
        for (int mf = 0; mf < 4; ++mf) {
            int r  = wm0 + mf * 16 + fr;
            int so = ((r * 64 + kq * 16) ^ ((r & 7) << 4)) >> 1;
            fa[mf] = *reinterpret_cast<const bf16x8*>(lbc + so);
        }
        #pragma unroll
        for (int nf = 0; nf < 4; ++nf) {
            int r  = wn0 + nf * 16 + fr;
            int so = ((r * 64 + kq * 16) ^ ((r & 7) << 4)) >> 1;
            fb[nf] = *reinterpret_cast<const bf16x8*>(lbc + 4096 + so);
        }
        __builtin_amdgcn_s_setprio(1);
        #pragma unroll
        for (int mf = 0; mf < 4; ++mf)
            #pragma unroll
            for (int nf = 0; nf < 4; ++nf)
                acc[mf][nf] = __builtin_amdgcn_mfma_f32_16x16x32_bf16(fa[mf], fb[nf], acc[mf][nf], 0, 0, 0);
        __builtin_amdgcn_s_setprio(0);
        __syncthreads();   // drains prefetch (vmcnt 0) + guards buffer reuse
    }

    const int rq = lane >> 4;
    #pragma unroll
    for (int nf = 0; nf < 4; ++nf) {
        int col = col0 + wn0 + nf * 16 + fr;
        if (col >= N) continue;
        float bia = bias[col];
        float g   = bn4[col];
        float be  = bn4[N + col];
        float mu  = bn4[2 * N + col];
        float va  = bn4[3 * N + col];
        float sc  = rsqrtf(va + EPS_) * g;
        #pragma unroll
        for (int mf = 0; mf < 4; ++mf) {
            #pragma unroll
            for (int r = 0; r < 4; ++r) {
                int row = row0 + wm0 + mf * 16 + rq * 4 + r;
                float v = acc[mf][nf][r] + bia;
                v = (v - mu) * sc + be;
                v = fmaxf(v, 0.f);
                if (ADD) v += bf2f((unsigned short)res[(size_t)row * N + col]);
                out[(size_t)row * N + col] = (short)f2bf(v);
            }
        }
    }
}

// ---------------- pooling + concat (+center direct from NHWC) -> bf16 feats [NSAMP][3C] ----------------
__global__ __launch_bounds__(256) void k_pool(const short* __restrict__ Hb,
                                              const short* __restrict__ nhwc,
                                              const int* __restrict__ cidx,
                                              short* __restrict__ feats) {
    int n = blockIdx.x;
    int b = n / NP_;
    const short* cen = nhwc + ((size_t)b * HW_ + cidx[n]) * C_;
    for (int c = threadIdx.x; c < C_; c += 256) {
        float s = 0.f, m = -INFINITY;
        #pragma unroll
        for (int j = 0; j < J_; j++) {
            float v = bf2f((unsigned short)Hb[((size_t)n * J_ + j) * C_ + c]);
            s += v;
            m = fmaxf(m, v);
        }
        feats[(size_t)n * 3 * C_ + c]          = (short)f2bf(s * (1.f / (float)J_));
        feats[(size_t)n * 3 * C_ + C_ + c]     = (short)f2bf(m);
        feats[(size_t)n * 3 * C_ + 2 * C_ + c] = cen[c];
    }
}

// ---------------- final projection (P bf16) ----------------
__global__ __launch_bounds__(256) void k_final(const short* __restrict__ P,
                                               const float* __restrict__ W2,
                                               const float* __restrict__ b2,
                                               float* __restrict__ out) {
    int g = blockIdx.x * 256 + threadIdx.x;
    if (g >= NSAMP * 2 * J_) return;
    int m = g / (2 * J_);
    int o = g % (2 * J_);
    const short* pr = P + (size_t)m * C_;
    const float* wr = W2 + (size_t)o * C_;
    float s = 0.f;
    for (int k = 0; k < C_; k += 4) {
        s = fmaf(bf2f((unsigned short)pr[k + 0]), wr[k + 0], s);
        s = fmaf(bf2f((unsigned short)pr[k + 1]), wr[k + 1], s);
        s = fmaf(bf2f((unsigned short)pr[k + 2]), wr[k + 2], s);
        s = fmaf(bf2f((unsigned short)pr[k + 3]), wr[k + 3], s);
    }
    out[g] = s + b2[o];
}

extern "C" void kernel_launch(void* const* d_in, const int* in_sizes, int n_in,
                              void* d_out, int out_size, void* d_ws, size_t ws_size,
                              hipStream_t stream) {
    const float* features = (const float*)d_in[0];
    const float* coords   = (const float*)d_in[1];
    const int*   center   = (const int*)d_in[2];
    const float* adj      = (const float*)d_in[3];
    const float* Wh       = (const float*)d_in[4];
    const float* bh       = (const float*)d_in[5];
    const float* bn_head  = (const float*)d_in[6];
    const float* Wres     = (const float*)d_in[7];
    const float* bres     = (const float*)d_in[8];
    const float* bn_res   = (const float*)d_in[9];
    const float* Wp1      = (const float*)d_in[10];
    const float* bp1      = (const float*)d_in[11];
    const float* bn_pred  = (const float*)d_in[12];
    const float* Wp2      = (const float*)d_in[13];
    const float* bp2      = (const float*)d_in[14];
    float* out = (float*)d_out;

    // ---- workspace layout ----
    char* ws = (char*)d_ws;
    short* nhwc  = (short*)ws;   ws += (size_t)B_ * HW_ * C_ * 2;     // bf16 NHWC
    short* bufX  = (short*)ws;   ws += (size_t)MROWS * C_ * 2;        // bf16 [MROWS,C]
    short* bufH  = (short*)ws;   ws += (size_t)MROWS * C_ * 2;
    short* AhB   = (short*)ws;   ws += (size_t)MROWS * C_ * 2;        // bf16 A
    short* featsB= (short*)ws;   ws += (size_t)NSAMP * 3 * C_ * 2;    // bf16 feats
    short* bufP  = (short*)ws;   ws += (size_t)NSAMP * C_ * 2;        // bf16 pred
    short* WtH   = (short*)ws;   ws += (size_t)NMAT * NPAD * C_ * 2;  // padded [512][480]
    short* WpH   = (short*)ws;   ws += (size_t)NPAD * 3 * C_ * 2;     // padded [512][1440]

    dim3 gg(4, MROWS / 128);          // 544 blocks (544 % 8 == 0)
    dim3 gp(4, NSAMP / 128);          // 32 blocks  (32 % 8 == 0)

    // merged transpose + weight-split
    k_prep<<<NT_ + NW_, 256, 0, stream>>>(features, Wh, Wres, Wp1, nhwc, WtH, WpH);

    // head block
    k_gather_mix<<<NSAMP, 256, 0, stream>>>(nhwc, coords, adj, AhB);
    k_gemm_mfma<false><<<gg, 256, 0, stream>>>(AhB, WtH, bh, bn_head,
                                               nullptr, bufH, MROWS, C_, C_);

    for (int i = 0; i < L_; i++) {
        int m1 = 1 + 2 * i, m2 = 2 + 2 * i;
        k_mix_bf16<<<NSAMP / 2, 256, 0, stream>>>(bufH, adj, AhB);
        k_gemm_mfma<false><<<gg, 256, 0, stream>>>(
            AhB, WtH + (size_t)m1 * NPAD * C_,
            bres + (size_t)(2 * i) * C_, bn_res + (size_t)(2 * i) * 4 * C_,
            nullptr, bufX, MROWS, C_, C_);
        k_mix_bf16<<<NSAMP / 2, 256, 0, stream>>>(bufX, adj, AhB);
        k_gemm_mfma<true><<<gg, 256, 0, stream>>>(
            AhB, WtH + (size_t)m2 * NPAD * C_,
            bres + (size_t)(2 * i + 1) * C_, bn_res + (size_t)(2 * i + 1) * 4 * C_,
            bufH, bufH, MROWS, C_, C_);
    }

    k_pool<<<NSAMP, 256, 0, stream>>>(bufH, nhwc, center, featsB);

    // pred: relu(bn(feats @ Wp1^T + bp1)); M=1024, N=480, K=1440
    k_gemm_mfma<false><<<gp, 256, 0, stream>>>(featsB, WpH, bp1, bn_pred,
                                               nullptr, bufP, NSAMP, C_, 3 * C_);

    k_final<<<(NSAMP * 2 * J_ + 255) / 256, 256, 0, stream>>>(bufP, Wp2, bp2, out);
}